// Round 4
// baseline (23049.519 us; speedup 1.0000x reference)
//
#include <hip/hip_runtime.h>
#include <math.h>

#define TMAX 16384
#define MDIM 16
#define NTHR 1024

// s_waitcnt imm: vmcnt=max(63), expcnt=max(7), lgkmcnt=0 -> 0xC07F
#define LGKM0() __builtin_amdgcn_s_waitcnt(0xc07f)

// ---- DPP-based full-wave (64-lane) max: VALU pipe only ----
template<int CTRL>
__device__ __forceinline__ float fmax_dpp(float v) {
    int o = __builtin_amdgcn_update_dpp(__float_as_int(v), __float_as_int(v),
                                        CTRL, 0xf, 0xf, false);
    return fmaxf(v, __int_as_float(o));
}
__device__ __forceinline__ float waveMax64(float v) {
    v = fmax_dpp<0x111>(v);   // row_shr:1
    v = fmax_dpp<0x112>(v);   // row_shr:2
    v = fmax_dpp<0x114>(v);   // row_shr:4
    v = fmax_dpp<0x118>(v);   // row_shr:8
    v = fmax_dpp<0x142>(v);   // row_bcast:15
    v = fmax_dpp<0x143>(v);   // row_bcast:31
    return __int_as_float(__builtin_amdgcn_readlane(__float_as_int(v), 63));
}
__device__ __forceinline__ float rfl(float v) {   // force wave-uniform -> SGPR
    return __int_as_float(__builtin_amdgcn_readfirstlane(__float_as_int(v)));
}
__device__ __forceinline__ float waveSumF(float v) {
    #pragma unroll
    for (int o = 32; o > 0; o >>= 1) v += __shfl_xor(v, o, 64);
    return v;
}
__device__ __forceinline__ double waveSumD(double v) {
    #pragma unroll
    for (int o = 32; o > 0; o >>= 1) v += __shfl_xor(v, o, 64);
    return v;
}

// ---- K0: x int -> float (enables SGPR s_loads of x rows in sequential kernel) ----
__global__ __launch_bounds__(256)
void xf_kernel(const int* __restrict__ x, float* __restrict__ xf) {
    int i = blockIdx.x * 256 + threadIdx.x;        // 65536 threads, 1 int4 each
    int4 v = ((const int4*)x)[i];
    float4 f = make_float4((float)v.x, (float)v.y, (float)v.z, (float)v.w);
    ((float4*)xf)[i] = f;
}

// ---- K1: Dem[t] = max_s em[t,s] (t-parallel across the whole chip) ----
__global__ __launch_bounds__(256, 1)
void dem_kernel(const float* __restrict__ xf,
                const float* __restrict__ lam1,
                const float* __restrict__ lam2,
                const float* __restrict__ lam3,
                float* __restrict__ Dem) {
    __shared__ float red[4];
    const int tid = threadIdx.x, lane = tid & 63, wv = tid >> 6;
    const int sbase = tid * 8;                      // 8 states per thread, in registers
    float llc[8][16];
    float ls[8];
    #pragma unroll
    for (int j = 0; j < 8; ++j) {
        int s = sbase + j;
        int d1 = s >> 7, d2 = (s >> 3) & 15, d3 = s & 7;
        float sum = 0.f;
        #pragma unroll
        for (int m = 0; m < 16; ++m) {
            float la = lam1[d1*16+m] + lam2[d2*16+m] + lam3[d3*16+m];
            sum += la;
            llc[j][m] = __logf(la);
        }
        ls[j] = sum;
    }
    const int t0 = blockIdx.x * 64;
    for (int ti = 0; ti < 64; ++ti) {
        int t = t0 + ti;
        const float* __restrict__ xr = xf + t * 16;
        float vm = -3.4e38f;
        #pragma unroll
        for (int j = 0; j < 8; ++j) {
            float d = 0.f;
            #pragma unroll
            for (int m = 0; m < 16; ++m) d = fmaf(xr[m], llc[j][m], d);
            vm = fmaxf(vm, d - ls[j]);
        }
        vm = waveMax64(vm);
        if (lane == 0) red[wv] = vm;
        __syncthreads();
        if (tid == 0)
            Dem[t] = fmaxf(fmaxf(red[0], red[1]), fmaxf(red[2], red[3]));
        __syncthreads();
    }
}

// ---- Main: factorial-HMM forward, scaled linear domain, single workgroup ----
// 1024 threads / 16 waves, 2 states/thread; state s = d1*128 + d2*8 + d3;
// s0 = 2*tid  ->  d1 = wv (wave-uniform), d2 = (tid>>2)&15, d3 pair = 2*(tid&3).
__global__ __launch_bounds__(NTHR, 4)
void fhmm_forward_kernel(const int* __restrict__ x,
                         const float* __restrict__ xf,
                         const float* __restrict__ DemG,
                         const float* __restrict__ lam1,
                         const float* __restrict__ lam2,
                         const float* __restrict__ lam3,
                         const float* __restrict__ logA1,
                         const float* __restrict__ logA2,
                         const float* __restrict__ logA3,
                         const float* __restrict__ logpi1,
                         const float* __restrict__ logpi2,
                         const float* __restrict__ logpi3,
                         float* __restrict__ out)
{
    __shared__ __align__(16) float alpha[2048];      // [p1*128 + p2*8 + p3]
    __shared__ float c1buf[16 * 132];                // [p2*132 + d1*8 + p3]
    __shared__ float c2buf[16 * 168];                // [d1*168 + d2*10 + p3]
    __shared__ float wmA[16];
    __shared__ float sD[1];
    __shared__ float lgtbl[32];
    __shared__ double lgpart[16];
    __shared__ float sredf[16];

    const int tid  = threadIdx.x;
    const int lane = tid & 63;
    const int wv   = tid >> 6;
    const int s0   = tid * 2;
    const int d1   = wv;                   // s0>>7 == tid>>6
    const int d2   = (tid >> 2) & 15;
    const int d3p  = 2 * (tid & 3);        // owns d3p, d3p+1

    // Stage-1: rows r1,r1+1 (wave-uniform), col cS1 = p2*8+p3
    const int r1  = 2 * (wv >> 1);
    const int cS1 = tid & 127;             // == (wv&1)*64 + lane
    // Stage-2 (wave-local, d1 = wv): lane -> (d2 rows {2*dps, 2*dps+1}, col p3s)
    const int dps = lane >> 3;
    const int p3s = lane & 7;

    if (tid < 32) lgtbl[tid] = lgammaf((float)tid + 1.0f);

    // A1 rows -> SGPR (wave-uniform)
    float sa1a[16], sa1b[16];
    #pragma unroll
    for (int p = 0; p < 16; ++p) {
        sa1a[p] = rfl(__expf(logA1[r1 * 16 + p]));
        sa1b[p] = rfl(__expf(logA1[(r1 + 1) * 16 + p]));
    }
    // A2 rows for S2 (lane-dependent) -> VGPR
    float a2a[16], a2b[16];
    #pragma unroll
    for (int p = 0; p < 16; ++p) {
        a2a[p] = __expf(logA2[(2 * dps) * 16 + p]);
        a2b[p] = __expf(logA2[(2 * dps + 1) * 16 + p]);
    }
    // A3 rows for S3 -> VGPR
    float a3a[8], a3b[8];
    #pragma unroll
    for (int p = 0; p < 8; ++p) {
        a3a[p] = __expf(logA3[(d3p) * 8 + p]);
        a3b[p] = __expf(logA3[(d3p + 1) * 8 + p]);
    }
    // emission params
    float rl0[16], rl1[16];
    float lamsum0 = 0.f, lamsum1 = 0.f;
    #pragma unroll
    for (int m = 0; m < MDIM; ++m) {
        float l12 = lam1[d1 * MDIM + m] + lam2[d2 * MDIM + m];
        float la  = l12 + lam3[(d3p) * MDIM + m];
        float lb  = l12 + lam3[(d3p + 1) * MDIM + m];
        lamsum0 += la; lamsum1 += lb;
        rl0[m] = __logf(la);
        rl1[m] = __logf(lb);
    }
    __syncthreads();

    // one-time: sum_t sum_m lgamma(x+1)
    {
        double lg = 0.0;
        const int4* x4 = (const int4*)x;
        for (int i = tid; i < TMAX * MDIM / 4; i += NTHR) {
            int4 v = x4[i];
            lg += (double)(lgtbl[v.x & 31] + lgtbl[v.y & 31] +
                           lgtbl[v.z & 31] + lgtbl[v.w & 31]);
        }
        lg = waveSumD(lg);
        if (lane == 0) lgpart[wv] = lg;
    }

    // ---- t = 0 ----
    double OFF = 0.0;
    {
        const float* __restrict__ xr = xf;   // t=0 row
        float e0 = 0.f, e1 = 0.f;
        #pragma unroll
        for (int m = 0; m < MDIM; ++m) {
            float xv = xr[m];
            e0 = fmaf(xv, rl0[m], e0);
            e1 = fmaf(xv, rl1[m], e1);
        }
        float lp12 = logpi1[d1] + logpi2[d2];
        float va = e0 - lamsum0 + lp12 + logpi3[d3p];
        float vb = e1 - lamsum1 + lp12 + logpi3[d3p + 1];
        float wm = waveMax64(fmaxf(va, vb));
        if (lane == 0) wmA[wv] = wm;
        __syncthreads();
        float M0 = wmA[0];
        #pragma unroll
        for (int i = 1; i < 16; ++i) M0 = fmaxf(M0, wmA[i]);
        float u0 = __expf(va - M0), u1 = __expf(vb - M0);
        alpha[s0] = u0; alpha[s0 + 1] = u1;
        float wa = waveMax64(fmaxf(u0, u1));
        __syncthreads();                    // all reads of wmA done
        if (lane == 0) wmA[wv] = wa;
        if (tid == 0) OFF = (double)M0;
        __syncthreads();                    // wmA/alpha ready
    }

    float Dv = 0.f;

    // ---- main sequential recurrence: 2 barriers/step ----
    for (int t = 1; t < TMAX; ++t) {
        const float* __restrict__ xr = xf + (t << 4);
        float Dt = DemG[t];

        // wave 0: previous-step alpha-max combine; publish D = Dem[t] + log(mp)
        if (wv == 0) {
            float mp = waveMax64(wmA[lane & 15]);
            Dv = Dt + __logf(fmaxf(mp, 1e-30f));
            if (lane == 0) sD[0] = Dv;
        }

        // Stage 1: c1[p2*132 + r*8 + p3] = sum_p1 A1[r,p1] * alpha[p1*128 + cS1]
        {
            float a0 = 0.f, a1 = 0.f;
            #pragma unroll
            for (int p1 = 0; p1 < 16; ++p1) {
                float av = alpha[p1 * 128 + cS1];
                a0 = fmaf(sa1a[p1], av, a0);
                a1 = fmaf(sa1b[p1], av, a1);
            }
            int wbase = (cS1 >> 3) * 132 + (cS1 & 7);
            c1buf[wbase + r1 * 8]       = a0;
            c1buf[wbase + (r1 + 1) * 8] = a1;
        }

        // emission for this thread's 2 states (xr is uniform -> scalar loads)
        float e0 = 0.f, e1 = 0.f;
        #pragma unroll
        for (int m = 0; m < MDIM; ++m) {
            float xv = xr[m];
            e0 = fmaf(xv, rl0[m], e0);
            e1 = fmaf(xv, rl1[m], e1);
        }
        e0 -= lamsum0; e1 -= lamsum1;
        __syncthreads();   // B1: c1 + sD ready

        // Stage 2 (wave-local, d1 = wv): c2[wv][d2][p3] = sum_p2 A2[d2,p2]*c1[p2][wv*8+p3]
        {
            float b0 = 0.f, b1 = 0.f;
            #pragma unroll
            for (int p2 = 0; p2 < 16; ++p2) {
                float cv = c1buf[p2 * 132 + (wv << 3) + p3s];   // 8-lane broadcast
                b0 = fmaf(a2a[p2], cv, b0);
                b1 = fmaf(a2b[p2], cv, b1);
            }
            int cb = wv * 168 + p3s;
            c2buf[cb + (2 * dps) * 10]     = b0;
            c2buf[cb + (2 * dps + 1) * 10] = b1;
        }
        LGKM0();           // same-wave LDS write->read ordering; no block barrier

        // Stage 3 (same wave) + pointwise
        {
            float D = (wv == 0) ? Dv : sD[0];
            const float2* c2v = (const float2*)(c2buf + wv * 168 + d2 * 10);
            float cv[8];
            #pragma unroll
            for (int j = 0; j < 4; ++j) {
                float2 q = c2v[j];
                cv[2*j] = q.x; cv[2*j+1] = q.y;
            }
            float g0 = 0.f, g1 = 0.f;
            #pragma unroll
            for (int p = 0; p < 8; ++p) {
                g0 = fmaf(a3a[p], cv[p], g0);
                g1 = fmaf(a3b[p], cv[p], g1);
            }
            float nu0 = __expf(e0 - D) * g0;
            float nu1 = __expf(e1 - D) * g1;
            *(float2*)(alpha + s0) = make_float2(nu0, nu1);
            float wa = waveMax64(fmaxf(nu0, nu1));
            if (lane == 0) wmA[wv] = wa;
            if (tid == 0) OFF += (double)Dv;
        }
        __syncthreads();   // B2: alpha + wmA ready for next step
    }

    // ---- final: logp = OFF + log(sum_s alpha) - lgam_total ----
    {
        float su = alpha[s0] + alpha[s0 + 1];
        su = waveSumF(su);
        if (lane == 0) sredf[wv] = su;
        __syncthreads();
        if (tid == 0) {
            float tot = 0.f;
            #pragma unroll
            for (int i = 0; i < 16; ++i) tot += sredf[i];
            double lgt = 0.0;
            #pragma unroll
            for (int i = 0; i < 16; ++i) lgt += lgpart[i];
            double res = OFF + (double)__logf(tot) - lgt;
            out[0] = (float)res;
        }
    }
}

extern "C" void kernel_launch(void* const* d_in, const int* in_sizes, int n_in,
                              void* d_out, int out_size, void* d_ws, size_t ws_size,
                              hipStream_t stream) {
    const int*   x      = (const int*)  d_in[0];
    const float* lam1   = (const float*)d_in[1];
    const float* lam2   = (const float*)d_in[2];
    const float* lam3   = (const float*)d_in[3];
    const float* logA1  = (const float*)d_in[4];
    const float* logA2  = (const float*)d_in[5];
    const float* logA3  = (const float*)d_in[6];
    const float* logpi1 = (const float*)d_in[7];
    const float* logpi2 = (const float*)d_in[8];
    const float* logpi3 = (const float*)d_in[9];
    float* out = (float*)d_out;

    float* xf  = (float*)d_ws;                    // 16384*16 floats = 1 MB
    float* Dem = xf + TMAX * MDIM;                // 16384 floats = 64 KB

    xf_kernel<<<dim3(256), dim3(256), 0, stream>>>(x, xf);
    dem_kernel<<<dim3(TMAX / 64), dim3(256), 0, stream>>>(xf, lam1, lam2, lam3, Dem);
    fhmm_forward_kernel<<<dim3(1), dim3(NTHR), 0, stream>>>(
        x, xf, Dem, lam1, lam2, lam3, logA1, logA2, logA3,
        logpi1, logpi2, logpi3, out);
}

// Round 5
// 16862.073 us; speedup vs baseline: 1.3669x; 1.3669x over previous
//
#include <hip/hip_runtime.h>
#include <math.h>

#define TMAX 16384
#define MDIM 16
#define SD   2048
#define NTHR 512

typedef unsigned int  uint;
typedef unsigned short ushort;

// s_waitcnt imm: vmcnt=max(63), expcnt=max(7), lgkmcnt=0 -> 0xC07F
#define LGKM0() __builtin_amdgcn_s_waitcnt(0xc07f)

// ---- DPP-based full-wave (64-lane) max ----
template<int CTRL>
__device__ __forceinline__ float fmax_dpp(float v) {
    int o = __builtin_amdgcn_update_dpp(__float_as_int(v), __float_as_int(v),
                                        CTRL, 0xf, 0xf, false);
    return fmaxf(v, __int_as_float(o));
}
__device__ __forceinline__ float waveMax64(float v) {
    v = fmax_dpp<0x111>(v);
    v = fmax_dpp<0x112>(v);
    v = fmax_dpp<0x114>(v);
    v = fmax_dpp<0x118>(v);
    v = fmax_dpp<0x142>(v);
    v = fmax_dpp<0x143>(v);
    return __int_as_float(__builtin_amdgcn_readlane(__float_as_int(v), 63));
}
__device__ __forceinline__ float rfl(float v) {
    return __int_as_float(__builtin_amdgcn_readfirstlane(__float_as_int(v)));
}
__device__ __forceinline__ float waveSumF(float v) {
    #pragma unroll
    for (int o = 32; o > 0; o >>= 1) v += __shfl_xor(v, o, 64);
    return v;
}

// float -> bf16 with round-to-nearest-even
__device__ __forceinline__ ushort f2bf(float f) {
    uint b = __float_as_uint(f);
    b = (b + 0x7FFFu + ((b >> 16) & 1u)) >> 16;
    return (ushort)b;
}

// ---- K0: x int -> float ----
__global__ __launch_bounds__(256)
void xf_kernel(const int* __restrict__ x, float* __restrict__ xf) {
    int i = blockIdx.x * 256 + threadIdx.x;
    int4 v = ((const int4*)x)[i];
    ((float4*)xf)[i] = make_float4((float)v.x, (float)v.y, (float)v.z, (float)v.w);
}

// ---- K1: SumAux -= sum_t sum_m lgamma(x+1) ----
__global__ __launch_bounds__(256)
void lgam_kernel(const int* __restrict__ x, float* __restrict__ SumAux) {
    int i = blockIdx.x * 256 + threadIdx.x;     // 65536 threads = TMAX*MDIM/4
    int4 v = ((const int4*)x)[i];
    float s = lgammaf((float)v.x + 1.f) + lgammaf((float)v.y + 1.f)
            + lgammaf((float)v.z + 1.f) + lgammaf((float)v.w + 1.f);
    s = waveSumF(s);
    if ((threadIdx.x & 63) == 0) atomicAdd(SumAux, -s);
}

// ---- K2: per-t emission row -> P[t,s] = exp(em - Dem[t]) (bf16); SumAux += sum Dem ----
__global__ __launch_bounds__(256, 1)
void emP_kernel(const float* __restrict__ xf,
                const float* __restrict__ lam1,
                const float* __restrict__ lam2,
                const float* __restrict__ lam3,
                ushort* __restrict__ P,
                float* __restrict__ SumAux) {
    __shared__ float red[4];
    const int tid = threadIdx.x, lane = tid & 63, wv = tid >> 6;
    const int sbase = tid * 8;                  // 8 states per thread, in registers
    float llc[8][16], ls[8];
    #pragma unroll
    for (int j = 0; j < 8; ++j) {
        int s = sbase + j;
        int d1 = s >> 7, d2 = (s >> 3) & 15, d3 = s & 7;
        float sum = 0.f;
        #pragma unroll
        for (int m = 0; m < 16; ++m) {
            float la = lam1[d1*16+m] + lam2[d2*16+m] + lam3[d3*16+m];
            sum += la;
            llc[j][m] = __logf(la);
        }
        ls[j] = sum;
    }
    const int t0 = blockIdx.x * 64;
    double sumD = 0.0;
    for (int ti = 0; ti < 64; ++ti) {
        int t = t0 + ti;
        const float* __restrict__ xr = xf + t * 16;
        float em[8];
        float vm = -3.4e38f;
        #pragma unroll
        for (int j = 0; j < 8; ++j) {
            float d = 0.f;
            #pragma unroll
            for (int m = 0; m < 16; ++m) d = fmaf(xr[m], llc[j][m], d);
            em[j] = d - ls[j];
            vm = fmaxf(vm, em[j]);
        }
        vm = waveMax64(vm);
        if (lane == 0) red[wv] = vm;
        __syncthreads();
        float Dem = fmaxf(fmaxf(red[0], red[1]), fmaxf(red[2], red[3]));
        uint4 w;
        w.x = (uint)f2bf(__expf(em[0]-Dem)) | ((uint)f2bf(__expf(em[1]-Dem)) << 16);
        w.y = (uint)f2bf(__expf(em[2]-Dem)) | ((uint)f2bf(__expf(em[3]-Dem)) << 16);
        w.z = (uint)f2bf(__expf(em[4]-Dem)) | ((uint)f2bf(__expf(em[5]-Dem)) << 16);
        w.w = (uint)f2bf(__expf(em[6]-Dem)) | ((uint)f2bf(__expf(em[7]-Dem)) << 16);
        *(uint4*)(P + (size_t)t * SD + sbase) = w;
        if (tid == 0) sumD += (double)Dem;
        __syncthreads();
    }
    if (tid == 0) atomicAdd(SumAux, (float)sumD);
}

// ---- K3: sequential forward recurrence, 512 threads / 8 waves ----
// State s = d1*128 + d2*8 + d3. Thread owns s0 = 4*tid .. s0+3
// (d1 = tid>>5, d2 = (tid>>1)&15, d3 = 4*(tid&1)+k).
__global__ __launch_bounds__(NTHR, 2)
void fhmm_forward_kernel(const ushort* __restrict__ P,
                         const float* __restrict__ SumAux,
                         const float* __restrict__ logA1,
                         const float* __restrict__ logA2,
                         const float* __restrict__ logA3,
                         const float* __restrict__ logpi1,
                         const float* __restrict__ logpi2,
                         const float* __restrict__ logpi3,
                         float* __restrict__ out)
{
    __shared__ __align__(16) float alpha[SD];          // [p1*128 + p2*8 + p3]
    __shared__ __align__(16) float c1T[16 * 8 * 20];   // [(d1*8 + p3)*20 + p2]
    __shared__ __align__(16) float c2b[16 * 200];      // [d1*200 + d2*12 + p3]
    __shared__ float wmA[8];
    __shared__ float sD[1];
    __shared__ float sred[8];

    const int tid  = threadIdx.x;
    const int lane = tid & 63;
    const int wv   = tid >> 6;
    const int s0   = tid * 4;
    const int d1   = tid >> 5;            // = 2*wv + (lane>>5)
    const int d2   = (tid >> 1) & 15;
    const int d3q  = 4 * (tid & 1);       // owns d3q..d3q+3

    // S1: col c = tid&127 (= (p2,p3)), output d1-rows r1..r1+3 (wave-uniform)
    const int cS1 = tid & 127;
    const int r1  = 4 * (tid >> 7);       // uniform per wave: 4*(wv>>1)
    const int p2c = cS1 >> 3, p3c = cS1 & 7;
    const int c1w = p3c * 20 + p2c;       // + (r1+k)*160
    // S2 (wave-local d1): lane -> d1s, p3v, d2 rows 4*(lane31>>3)+k
    const int lane31 = lane & 31;
    const int d1s  = 2 * wv + (lane >> 5);
    const int p3v  = lane31 & 7;
    const int d2r  = 4 * (lane31 >> 3);
    const int c1rb = (d1s * 8 + p3v) * 20;          // + p2 contiguous -> b128
    const int c2wb = d1s * 200 + p3v;               // + (d2r+k)*12
    // S3: reads c2 row (d1, d2)
    const int c2rb = d1 * 200 + d2 * 12;

    // ---- constant matrices into registers ----
    float sa1[4][16];                      // A1 rows r1..r1+3 (wave-uniform -> SGPR)
    #pragma unroll
    for (int k = 0; k < 4; ++k)
        #pragma unroll
        for (int p = 0; p < 16; ++p)
            sa1[k][p] = rfl(__expf(logA1[(r1 + k) * 16 + p]));
    float a2[4][16];                       // A2 rows d2r..d2r+3 (lane-dependent)
    #pragma unroll
    for (int k = 0; k < 4; ++k)
        #pragma unroll
        for (int p = 0; p < 16; ++p)
            a2[k][p] = __expf(logA2[(d2r + k) * 16 + p]);
    float a3[4][8];                        // A3 rows d3q..d3q+3
    #pragma unroll
    for (int k = 0; k < 4; ++k)
        #pragma unroll
        for (int p = 0; p < 8; ++p)
            a3[k][p] = __expf(logA3[(d3q + k) * 8 + p]);

    const uint2* __restrict__ Pv = (const uint2*)P;   // 4 bf16 per uint2

    // ---- t = 0: alpha0 = P0 * pi ----
    double OFF = 0.0;
    {
        uint2 p0 = Pv[tid];                            // t=0, states s0..s0+3
        float pf0 = __uint_as_float(p0.x << 16);
        float pf1 = __uint_as_float(p0.x & 0xFFFF0000u);
        float pf2 = __uint_as_float(p0.y << 16);
        float pf3 = __uint_as_float(p0.y & 0xFFFF0000u);
        float lp = logpi1[d1] + logpi2[d2];
        float4 av;
        av.x = pf0 * __expf(lp + logpi3[d3q + 0]);
        av.y = pf1 * __expf(lp + logpi3[d3q + 1]);
        av.z = pf2 * __expf(lp + logpi3[d3q + 2]);
        av.w = pf3 * __expf(lp + logpi3[d3q + 3]);
        *(float4*)(alpha + s0) = av;
        float wa = waveMax64(fmaxf(fmaxf(av.x, av.y), fmaxf(av.z, av.w)));
        if (lane == 0) wmA[wv] = wa;
        __syncthreads();
    }

    // prefetch P row t=1
    uint2 Pc = Pv[512 + tid];

    // ---- sequential recurrence: 2 barriers/step ----
    for (int t = 1; t < TMAX; ++t) {
        int tn = (t + 1 < TMAX) ? (t + 1) : t;
        uint2 Pn = Pv[tn * 512 + tid];

        // wave 0: combine prev-step alpha maxes; publish invm; accumulate OFF
        if (wv == 0) {
            float mp = waveMax64(wmA[lane & 7]);
            float inv = __builtin_amdgcn_rcpf(mp);
            if (lane == 0) {
                sD[0] = inv;
                OFF += (double)__logf(mp);
            }
        }

        // Stage 1: c1[r1+k][(p2,p3)] = sum_p1 A1[r1+k,p1] * alpha[p1*128 + cS1]
        {
            float a0 = 0.f, a1 = 0.f, a2s = 0.f, a3s = 0.f;
            #pragma unroll
            for (int p1 = 0; p1 < 16; ++p1) {
                float av = alpha[p1 * 128 + cS1];
                a0  = fmaf(sa1[0][p1], av, a0);
                a1  = fmaf(sa1[1][p1], av, a1);
                a2s = fmaf(sa1[2][p1], av, a2s);
                a3s = fmaf(sa1[3][p1], av, a3s);
            }
            c1T[(r1 + 0) * 160 + c1w] = a0;
            c1T[(r1 + 1) * 160 + c1w] = a1;
            c1T[(r1 + 2) * 160 + c1w] = a2s;
            c1T[(r1 + 3) * 160 + c1w] = a3s;
        }
        __syncthreads();   // B1: c1T + sD ready

        // Stage 2 (wave-local): c2[d1s][d2r+k][p3v] = sum_p2 A2[d2r+k,p2]*c1T[d1s,p3v][p2]
        {
            const float4* c1v = (const float4*)(c1T + c1rb);
            float b0 = 0.f, b1 = 0.f, b2 = 0.f, b3 = 0.f;
            #pragma unroll
            for (int pq = 0; pq < 4; ++pq) {
                float4 q = c1v[pq];
                b0 = fmaf(a2[0][4*pq+0], q.x, b0); b1 = fmaf(a2[1][4*pq+0], q.x, b1);
                b2 = fmaf(a2[2][4*pq+0], q.x, b2); b3 = fmaf(a2[3][4*pq+0], q.x, b3);
                b0 = fmaf(a2[0][4*pq+1], q.y, b0); b1 = fmaf(a2[1][4*pq+1], q.y, b1);
                b2 = fmaf(a2[2][4*pq+1], q.y, b2); b3 = fmaf(a2[3][4*pq+1], q.y, b3);
                b0 = fmaf(a2[0][4*pq+2], q.z, b0); b1 = fmaf(a2[1][4*pq+2], q.z, b1);
                b2 = fmaf(a2[2][4*pq+2], q.z, b2); b3 = fmaf(a2[3][4*pq+2], q.z, b3);
                b0 = fmaf(a2[0][4*pq+3], q.w, b0); b1 = fmaf(a2[1][4*pq+3], q.w, b1);
                b2 = fmaf(a2[2][4*pq+3], q.w, b2); b3 = fmaf(a2[3][4*pq+3], q.w, b3);
            }
            c2b[c2wb + (d2r + 0) * 12] = b0;
            c2b[c2wb + (d2r + 1) * 12] = b1;
            c2b[c2wb + (d2r + 2) * 12] = b2;
            c2b[c2wb + (d2r + 3) * 12] = b3;
        }
        LGKM0();           // wave-local write->read ordering (same wave produced our rows)

        // Stage 3 + pointwise: alpha'[s0+k] = P[t,s0+k] * invm * sum_p3 A3[d3q+k,p3]*c2[d1,d2,p3]
        {
            float inv = sD[0];
            const float4* c2v = (const float4*)(c2b + c2rb);
            float4 qa = c2v[0], qb = c2v[1];
            float cv[8] = {qa.x, qa.y, qa.z, qa.w, qb.x, qb.y, qb.z, qb.w};
            float g0 = 0.f, g1 = 0.f, g2 = 0.f, g3 = 0.f;
            #pragma unroll
            for (int p = 0; p < 8; ++p) {
                g0 = fmaf(a3[0][p], cv[p], g0);
                g1 = fmaf(a3[1][p], cv[p], g1);
                g2 = fmaf(a3[2][p], cv[p], g2);
                g3 = fmaf(a3[3][p], cv[p], g3);
            }
            float pf0 = __uint_as_float(Pc.x << 16);
            float pf1 = __uint_as_float(Pc.x & 0xFFFF0000u);
            float pf2 = __uint_as_float(Pc.y << 16);
            float pf3 = __uint_as_float(Pc.y & 0xFFFF0000u);
            float4 nu;
            nu.x = pf0 * g0 * inv;
            nu.y = pf1 * g1 * inv;
            nu.z = pf2 * g2 * inv;
            nu.w = pf3 * g3 * inv;
            *(float4*)(alpha + s0) = nu;
            float wa = waveMax64(fmaxf(fmaxf(nu.x, nu.y), fmaxf(nu.z, nu.w)));
            if (lane == 0) wmA[wv] = wa;
        }
        Pc = Pn;
        __syncthreads();   // B2: alpha + wmA ready
    }

    // ---- final: logp = OFF + log(sum alpha) + (SumDem - Sumlgamma) ----
    {
        float su = alpha[s0] + alpha[s0+1] + alpha[s0+2] + alpha[s0+3];
        su = waveSumF(su);
        if (lane == 0) sred[wv] = su;
        __syncthreads();
        if (tid == 0) {
            float tot = 0.f;
            #pragma unroll
            for (int i = 0; i < 8; ++i) tot += sred[i];
            double res = OFF + (double)__logf(tot) + (double)SumAux[0];
            out[0] = (float)res;
        }
    }
}

extern "C" void kernel_launch(void* const* d_in, const int* in_sizes, int n_in,
                              void* d_out, int out_size, void* d_ws, size_t ws_size,
                              hipStream_t stream) {
    const int*   x      = (const int*)  d_in[0];
    const float* lam1   = (const float*)d_in[1];
    const float* lam2   = (const float*)d_in[2];
    const float* lam3   = (const float*)d_in[3];
    const float* logA1  = (const float*)d_in[4];
    const float* logA2  = (const float*)d_in[5];
    const float* logA3  = (const float*)d_in[6];
    const float* logpi1 = (const float*)d_in[7];
    const float* logpi2 = (const float*)d_in[8];
    const float* logpi3 = (const float*)d_in[9];
    float* out = (float*)d_out;

    // ws layout: [SumAux f32 (256B pad)] [xf: TMAX*16 f32 = 1MB] [P: TMAX*2048 bf16 = 64MB]
    float*  SumAux = (float*)d_ws;
    float*  xf     = (float*)((char*)d_ws + 256);
    ushort* P      = (ushort*)((char*)d_ws + 256 + (size_t)TMAX * MDIM * 4);

    hipMemsetAsync(SumAux, 0, sizeof(float), stream);
    xf_kernel  <<<dim3(256), dim3(256), 0, stream>>>(x, xf);
    lgam_kernel<<<dim3(256), dim3(256), 0, stream>>>(x, SumAux);
    emP_kernel <<<dim3(TMAX / 64), dim3(256), 0, stream>>>(xf, lam1, lam2, lam3, P, SumAux);
    fhmm_forward_kernel<<<dim3(1), dim3(NTHR), 0, stream>>>(
        P, SumAux, logA1, logA2, logA3, logpi1, logpi2, logpi3, out);
}

// Round 6
// 13323.022 us; speedup vs baseline: 1.7301x; 1.2656x over previous
//
#include <hip/hip_runtime.h>
#include <math.h>

#define TMAX 16384
#define MDIM 16
#define SD   2048

typedef unsigned int  uint;
typedef unsigned short ushort;
typedef __attribute__((ext_vector_type(8))) short short8;
typedef __attribute__((ext_vector_type(4))) float floatx4;
typedef __attribute__((ext_vector_type(2))) uint uintx2;

// ---- DPP-based full-wave (64-lane) max ----
template<int CTRL>
__device__ __forceinline__ float fmax_dpp(float v) {
    int o = __builtin_amdgcn_update_dpp(__float_as_int(v), __float_as_int(v),
                                        CTRL, 0xf, 0xf, false);
    return fmaxf(v, __int_as_float(o));
}
__device__ __forceinline__ float waveMax64(float v) {
    v = fmax_dpp<0x111>(v);
    v = fmax_dpp<0x112>(v);
    v = fmax_dpp<0x114>(v);
    v = fmax_dpp<0x118>(v);
    v = fmax_dpp<0x142>(v);
    v = fmax_dpp<0x143>(v);
    return __int_as_float(__builtin_amdgcn_readlane(__float_as_int(v), 63));
}
__device__ __forceinline__ float waveSumF(float v) {
    #pragma unroll
    for (int o = 32; o > 0; o >>= 1) v += __shfl_xor(v, o, 64);
    return v;
}

// bf16 helpers (RNE)
__device__ __forceinline__ short f2bfs(float f) {
    uint u = __float_as_uint(f);
    return (short)((u + 0x7FFFu + ((u >> 16) & 1u)) >> 16);
}
__device__ __forceinline__ uint pkbf(float a, float b) {
    uint ua = __float_as_uint(a), ub = __float_as_uint(b);
    ua = (ua + 0x7FFFu + ((ua >> 16) & 1u)) >> 16;
    ub = (ub + 0x7FFFu + ((ub >> 16) & 1u)) & 0xFFFF0000u;
    return ua | ub;
}
__device__ __forceinline__ float bfl(uint u) { return __uint_as_float(u << 16); }
__device__ __forceinline__ float bfh(uint u) { return __uint_as_float(u & 0xFFFF0000u); }

// ---- K0: x int -> float ----
__global__ __launch_bounds__(256)
void xf_kernel(const int* __restrict__ x, float* __restrict__ xf) {
    int i = blockIdx.x * 256 + threadIdx.x;
    int4 v = ((const int4*)x)[i];
    ((float4*)xf)[i] = make_float4((float)v.x, (float)v.y, (float)v.z, (float)v.w);
}

// ---- K1: SumAux -= sum_t sum_m lgamma(x+1) ----
__global__ __launch_bounds__(256)
void lgam_kernel(const int* __restrict__ x, float* __restrict__ SumAux) {
    int i = blockIdx.x * 256 + threadIdx.x;
    int4 v = ((const int4*)x)[i];
    float s = lgammaf((float)v.x + 1.f) + lgammaf((float)v.y + 1.f)
            + lgammaf((float)v.z + 1.f) + lgammaf((float)v.w + 1.f);
    s = waveSumF(s);
    if ((threadIdx.x & 63) == 0) atomicAdd(SumAux, -s);
}

// ---- K2: P_perm[t][slot] = exp(em[t,s(slot)] - Dem[t]) (bf16), slot order = K3's
//      (wave, lane, reg) ownership; SumAux += sum_t Dem[t] ----
__global__ __launch_bounds__(256, 1)
void emP_kernel(const float* __restrict__ xf,
                const float* __restrict__ lam1,
                const float* __restrict__ lam2,
                const float* __restrict__ lam3,
                ushort* __restrict__ P,
                float* __restrict__ SumAux) {
    __shared__ float red[4];
    const int tid = threadIdx.x, lane = tid & 63, wv = tid >> 6;
    int sidx[8];
    #pragma unroll
    for (int j = 0; j < 8; ++j) {
        int o = tid * 8 + j;
        int w = o >> 8, ln = (o >> 2) & 63, rg = o & 3;
        int qq = ln >> 4, nn = ln & 15;
        sidx[j] = (4*(w & 3) + rg) * 128 + nn * 8 + 4*(w >> 2) + qq;
    }
    float llc[8][16], ls[8];
    #pragma unroll
    for (int j = 0; j < 8; ++j) {
        int s = sidx[j];
        int d1 = s >> 7, d2 = (s >> 3) & 15, d3 = s & 7;
        float sum = 0.f;
        #pragma unroll
        for (int m = 0; m < 16; ++m) {
            float la = lam1[d1*16+m] + lam2[d2*16+m] + lam3[d3*16+m];
            sum += la;
            llc[j][m] = __logf(la);
        }
        ls[j] = sum;
    }
    const int t0 = blockIdx.x * 64;
    double sumD = 0.0;
    for (int ti = 0; ti < 64; ++ti) {
        int t = t0 + ti;
        const float* __restrict__ xr = xf + t * 16;
        float em[8];
        float vm = -3.4e38f;
        #pragma unroll
        for (int j = 0; j < 8; ++j) {
            float d = 0.f;
            #pragma unroll
            for (int m = 0; m < 16; ++m) d = fmaf(xr[m], llc[j][m], d);
            em[j] = d - ls[j];
            vm = fmaxf(vm, em[j]);
        }
        vm = waveMax64(vm);
        if (lane == 0) red[wv] = vm;
        __syncthreads();
        float Dem = fmaxf(fmaxf(red[0], red[1]), fmaxf(red[2], red[3]));
        uint4 w;
        w.x = pkbf(__expf(em[0]-Dem), __expf(em[1]-Dem));
        w.y = pkbf(__expf(em[2]-Dem), __expf(em[3]-Dem));
        w.z = pkbf(__expf(em[4]-Dem), __expf(em[5]-Dem));
        w.w = pkbf(__expf(em[6]-Dem), __expf(em[7]-Dem));
        *(uint4*)(P + (size_t)t * SD + tid * 8) = w;
        if (tid == 0) sumD += (double)Dem;
        __syncthreads();
    }
    if (tid == 0) atomicAdd(SumAux, (float)sumD);
}

// ---- K3: sequential recurrence, 512 threads / 8 waves, MFMA stages ----
// Contraction order p1 -> p3 -> p2. Each stage = 1 mfma_f32_16x16x32_bf16 per wave,
// data in A-operand (A[m=lane&15][k=quad*8+j]), constants in B ([k=quad*8+j][n=lane&15]),
// D in C-layout (row=4*quad+reg, col=lane&15).
__global__ __launch_bounds__(512, 2)
void fhmm_forward_kernel(const ushort* __restrict__ P,
                         const float* __restrict__ SumAux,
                         const float* __restrict__ logA1,
                         const float* __restrict__ logA2,
                         const float* __restrict__ logA3,
                         const float* __restrict__ logpi1,
                         const float* __restrict__ logpi2,
                         const float* __restrict__ logpi3,
                         float* __restrict__ out)
{
    // alpha (bf16): [c = p2*8+p3 (128)][k = p1 (16)], 8-elt blocks XOR-swizzled by (c>>3)&1
    __shared__ __align__(16) short albf[128 * 16];
    // C1 (bf16): [r = p2*16 + d1 (256)][p3 (8)]
    __shared__ __align__(16) short c1b[256 * 8];
    // C2 (bf16): [rr = d3*16 + d1 (128)][p2 (16)]
    __shared__ __align__(16) short c2b[128 * 16];
    __shared__ __align__(16) short zbuf[8];
    __shared__ float wmA[8];
    __shared__ float sD[1];
    __shared__ float sred[8];

    const int tid  = threadIdx.x;
    const int lane = tid & 63;
    const int wv   = tid >> 6;
    const int q    = lane >> 4;
    const int ml   = lane & 15;

    if (tid < 8) zbuf[tid] = 0;

    // ---- constant B-fragments ----
    short8 bA1, bA2, bA3;
    #pragma unroll
    for (int j = 0; j < 8; ++j) {
        int k = 8 * q + j;
        // S1: B[k=p1][n=d1] = A1[d1=n][p1=k]
        bA1[j] = (k < 16) ? f2bfs(__expf(logA1[ml * 16 + k])) : (short)0;
        // S3: B[k=p2][n=d2] = A2[d2=n][p2=k]
        bA2[j] = (k < 16) ? f2bfs(__expf(logA2[ml * 16 + k])) : (short)0;
        // S2: block-diag B[p3+8e][d3+8e'] = (e==e') * A3[d3][p3];  e=q, e'=ml>>3, p3=j
        bA3[j] = (q < 2 && q == (ml >> 3)) ? f2bfs(__expf(logA3[(ml & 7) * 8 + j])) : (short)0;
    }

    const int d1b  = 4 * (wv & 3);
    const int p2b0 = 4 * (wv >> 2);
    const int p2b1 = p2b0 + 8;
    const int d3b  = 4 * (wv >> 2);

    // ---- A-fragment read pointers (loop-invariant) ----
    // S1: c = 16w + ml, logical k-block q, phys block q ^ ((c>>3)&1)
    const short* pS1 = (q < 2)
        ? &albf[(16 * wv + ml) * 16 + ((q ^ ((ml >> 3) & 1)) << 3)] : zbuf;
    // S2: A[ml][k<8] = C1[batch_e0(ml)][p3], A[ml][8..15] = C1[batch_e1(ml)][p3]
    const short* pS2 = (q == 0)
        ? &c1b[((p2b0 + (ml & 3)) * 16 + d1b + (ml >> 2)) * 8]
        : (q == 1) ? &c1b[((p2b1 + (ml & 3)) * 16 + d1b + (ml >> 2)) * 8] : zbuf;
    // S3: A[ml][k=p2] = C2[(d3b + ml>>2)*16 + d1b + (ml&3)][p2], k-halves by q
    const short* pS3 = (q < 2)
        ? &c2b[((d3b + (ml >> 2)) * 16 + d1b + (ml & 3)) * 16 + 8 * q] : zbuf;

    // ---- D write pointers ----
    // S1 D: m=4q+reg -> p2 = 2w + (q>>1), p3 = 4(q&1)+reg; n=ml=d1
    short* wS1 = &c1b[((2 * wv + (q >> 1)) * 16 + ml) * 8 + 4 * (q & 1)];
    // S2 D: d1 = d1b+q, p2 = p2b_e + reg, d3 = ml&7, e = ml>>3
    short* wS2 = &c2b[((ml & 7) * 16 + d1b + q) * 16 + ((ml >> 3) ? p2b1 : p2b0)];
    // S3 D: d1 = d1b+reg, d2 = ml, d3 = d3b+q -> alpha c = ml*8 + d3b + q, k = d1 (swizzled)
    const int cc = ml * 8 + d3b + q;
    short* wS3 = &albf[cc * 16 + (((d1b >> 3) ^ ((cc >> 3) & 1)) << 3) + (d1b & 4)];

    __syncthreads();   // zbuf ready

    // ---- t = 0: alpha0 = P0 * pi (written via the S3 ownership/path) ----
    double OFF = 0.0;
    float nu0, nu1, nu2, nu3;
    {
        uintx2 p0 = *(const uintx2*)(P + (size_t)tid * 4);
        float lp23 = logpi2[ml] + logpi3[d3b + q];
        nu0 = bfl(p0.x) * __expf(logpi1[d1b + 0] + lp23);
        nu1 = bfh(p0.x) * __expf(logpi1[d1b + 1] + lp23);
        nu2 = bfl(p0.y) * __expf(logpi1[d1b + 2] + lp23);
        nu3 = bfh(p0.y) * __expf(logpi1[d1b + 3] + lp23);
        ((uintx2*)wS3)[0] = (uintx2){pkbf(nu0, nu1), pkbf(nu2, nu3)};
        float wa = waveMax64(fmaxf(fmaxf(nu0, nu1), fmaxf(nu2, nu3)));
        if (lane == 0) wmA[wv] = wa;
        __syncthreads();
    }

    uintx2 Pc = *(const uintx2*)(P + (size_t)2048 + tid * 4);

    // ---- sequential recurrence ----
    for (int t = 1; t < TMAX; ++t) {
        int tn = (t + 1 < TMAX) ? t + 1 : t;
        uintx2 Pn = *(const uintx2*)(P + (size_t)tn * 2048 + tid * 4);

        // wave 0: combine prev alpha maxes -> publish inv scale, accumulate OFF
        if (wv == 0) {
            float mp = waveMax64(wmA[lane & 7]);
            if (lane == 0) {
                float mg = fmaxf(mp, 1e-30f);
                sD[0] = __builtin_amdgcn_rcpf(mg);
                OFF += (double)__logf(mg);
            }
        }

        // Stage 1: C1 = A1 x alpha  (contract p1)
        {
            short8 af = *(const short8*)pS1;
            floatx4 acc = {0.f, 0.f, 0.f, 0.f};
            acc = __builtin_amdgcn_mfma_f32_16x16x32_bf16(af, bA1, acc, 0, 0, 0);
            ((uintx2*)wS1)[0] = (uintx2){pkbf(acc[0], acc[1]), pkbf(acc[2], acc[3])};
        }
        __syncthreads();   // B1: C1 + sD ready

        // Stage 2: C2 = A3 x C1 over p3 (2 batch-sets packed in K)
        {
            short8 af = *(const short8*)pS2;
            floatx4 acc = {0.f, 0.f, 0.f, 0.f};
            acc = __builtin_amdgcn_mfma_f32_16x16x32_bf16(af, bA3, acc, 0, 0, 0);
            ((uintx2*)wS2)[0] = (uintx2){pkbf(acc[0], acc[1]), pkbf(acc[2], acc[3])};
        }
        __syncthreads();   // B2: C2 ready

        // Stage 3: C3 = A2 x C2 over p2, + pointwise P*inv, write alpha'
        {
            short8 af = *(const short8*)pS3;
            floatx4 acc = {0.f, 0.f, 0.f, 0.f};
            acc = __builtin_amdgcn_mfma_f32_16x16x32_bf16(af, bA2, acc, 0, 0, 0);
            float inv = sD[0];
            nu0 = bfl(Pc.x) * acc[0] * inv;
            nu1 = bfh(Pc.x) * acc[1] * inv;
            nu2 = bfl(Pc.y) * acc[2] * inv;
            nu3 = bfh(Pc.y) * acc[3] * inv;
            ((uintx2*)wS3)[0] = (uintx2){pkbf(nu0, nu1), pkbf(nu2, nu3)};
            float wa = waveMax64(fmaxf(fmaxf(nu0, nu1), fmaxf(nu2, nu3)));
            if (lane == 0) wmA[wv] = wa;
        }
        Pc = Pn;
        __syncthreads();   // B3: alpha + wmA ready
    }

    // ---- final: logp = OFF + log(sum alpha) + (SumDem - Sumlgamma) ----
    {
        float su = waveSumF(nu0 + nu1 + nu2 + nu3);
        if (lane == 0) sred[wv] = su;
        __syncthreads();
        if (tid == 0) {
            float tot = 0.f;
            #pragma unroll
            for (int i = 0; i < 8; ++i) tot += sred[i];
            out[0] = (float)(OFF + (double)__logf(tot) + (double)SumAux[0]);
        }
    }
}

extern "C" void kernel_launch(void* const* d_in, const int* in_sizes, int n_in,
                              void* d_out, int out_size, void* d_ws, size_t ws_size,
                              hipStream_t stream) {
    const int*   x      = (const int*)  d_in[0];
    const float* lam1   = (const float*)d_in[1];
    const float* lam2   = (const float*)d_in[2];
    const float* lam3   = (const float*)d_in[3];
    const float* logA1  = (const float*)d_in[4];
    const float* logA2  = (const float*)d_in[5];
    const float* logA3  = (const float*)d_in[6];
    const float* logpi1 = (const float*)d_in[7];
    const float* logpi2 = (const float*)d_in[8];
    const float* logpi3 = (const float*)d_in[9];
    float* out = (float*)d_out;

    // ws: [SumAux (256B)] [xf: 1MB] [P_perm: TMAX*2048*2B = 64MB]
    float*  SumAux = (float*)d_ws;
    float*  xf     = (float*)((char*)d_ws + 256);
    ushort* P      = (ushort*)((char*)d_ws + 256 + (size_t)TMAX * MDIM * 4);

    hipMemsetAsync(SumAux, 0, sizeof(float), stream);
    xf_kernel  <<<dim3(256), dim3(256), 0, stream>>>(x, xf);
    lgam_kernel<<<dim3(256), dim3(256), 0, stream>>>(x, SumAux);
    emP_kernel <<<dim3(TMAX / 64), dim3(256), 0, stream>>>(xf, lam1, lam2, lam3, P, SumAux);
    fhmm_forward_kernel<<<dim3(1), dim3(512), 0, stream>>>(
        P, SumAux, logA1, logA2, logA3, logpi1, logpi2, logpi3, out);
}

// Round 7
// 9633.694 us; speedup vs baseline: 2.3926x; 1.3830x over previous
//
#include <hip/hip_runtime.h>
#include <math.h>

#define TMAX 16384
#define MDIM 16
#define SD   2048

typedef unsigned int  uint;
typedef unsigned short ushort;
typedef __attribute__((ext_vector_type(8))) short short8;
typedef __attribute__((ext_vector_type(4))) float floatx4;
typedef __attribute__((ext_vector_type(2))) uint uintx2;

// ---- DPP-based full-wave (64-lane) max ----
template<int CTRL>
__device__ __forceinline__ float fmax_dpp(float v) {
    int o = __builtin_amdgcn_update_dpp(__float_as_int(v), __float_as_int(v),
                                        CTRL, 0xf, 0xf, false);
    return fmaxf(v, __int_as_float(o));
}
__device__ __forceinline__ float waveMax64(float v) {
    v = fmax_dpp<0x111>(v);
    v = fmax_dpp<0x112>(v);
    v = fmax_dpp<0x114>(v);
    v = fmax_dpp<0x118>(v);
    v = fmax_dpp<0x142>(v);
    v = fmax_dpp<0x143>(v);
    return __int_as_float(__builtin_amdgcn_readlane(__float_as_int(v), 63));
}
__device__ __forceinline__ float waveSumF(float v) {
    #pragma unroll
    for (int o = 32; o > 0; o >>= 1) v += __shfl_xor(v, o, 64);
    return v;
}

// bf16 helpers (RNE)
__device__ __forceinline__ short f2bfs(float f) {
    uint u = __float_as_uint(f);
    return (short)((u + 0x7FFFu + ((u >> 16) & 1u)) >> 16);
}
__device__ __forceinline__ uint pkbf(float a, float b) {
    uint ua = __float_as_uint(a), ub = __float_as_uint(b);
    ua = (ua + 0x7FFFu + ((ua >> 16) & 1u)) >> 16;
    ub = (ub + 0x7FFFu + ((ub >> 16) & 1u)) & 0xFFFF0000u;
    return ua | ub;
}
__device__ __forceinline__ float bfl(uint u) { return __uint_as_float(u << 16); }
__device__ __forceinline__ float bfh(uint u) { return __uint_as_float(u & 0xFFFF0000u); }

// ---- K0: x int -> float ----
__global__ __launch_bounds__(256)
void xf_kernel(const int* __restrict__ x, float* __restrict__ xf) {
    int i = blockIdx.x * 256 + threadIdx.x;
    int4 v = ((const int4*)x)[i];
    ((float4*)xf)[i] = make_float4((float)v.x, (float)v.y, (float)v.z, (float)v.w);
}

// ---- K1: SumAux -= sum_t sum_m lgamma(x+1) ----
__global__ __launch_bounds__(256)
void lgam_kernel(const int* __restrict__ x, float* __restrict__ SumAux) {
    int i = blockIdx.x * 256 + threadIdx.x;
    int4 v = ((const int4*)x)[i];
    float s = lgammaf((float)v.x + 1.f) + lgammaf((float)v.y + 1.f)
            + lgammaf((float)v.z + 1.f) + lgammaf((float)v.w + 1.f);
    s = waveSumF(s);
    if ((threadIdx.x & 63) == 0) atomicAdd(SumAux, -s);
}

// ---- K2: P_perm[t][slot] = exp(em - Dem[t]) (bf16), slot order = K3 ownership:
//      slot o = wv*256 + lane*4 + r -> state s = (4*(lane>>4) + r)*128 + 16*wv + (lane&15)
__global__ __launch_bounds__(256, 1)
void emP_kernel(const float* __restrict__ xf,
                const float* __restrict__ lam1,
                const float* __restrict__ lam2,
                const float* __restrict__ lam3,
                ushort* __restrict__ P,
                float* __restrict__ SumAux) {
    __shared__ float red[4];
    const int tid = threadIdx.x, lane = tid & 63, wv = tid >> 6;
    int sidx[8];
    #pragma unroll
    for (int j = 0; j < 8; ++j) {
        int o  = tid * 8 + j;
        int r  = o & 3;
        int ln = (o >> 2) & 63;
        int wk = (o >> 8) & 7;
        int q  = ln >> 4, nn = ln & 15;
        sidx[j] = (4 * q + r) * 128 + 16 * wk + nn;
    }
    float llc[8][16], ls[8];
    #pragma unroll
    for (int j = 0; j < 8; ++j) {
        int s = sidx[j];
        int d1 = s >> 7, d2 = (s >> 3) & 15, d3 = s & 7;
        float sum = 0.f;
        #pragma unroll
        for (int m = 0; m < 16; ++m) {
            float la = lam1[d1*16+m] + lam2[d2*16+m] + lam3[d3*16+m];
            sum += la;
            llc[j][m] = __logf(la);
        }
        ls[j] = sum;
    }
    const int t0 = blockIdx.x * 64;
    double sumD = 0.0;
    for (int ti = 0; ti < 64; ++ti) {
        int t = t0 + ti;
        const float* __restrict__ xr = xf + t * 16;
        float em[8];
        float vm = -3.4e38f;
        #pragma unroll
        for (int j = 0; j < 8; ++j) {
            float d = 0.f;
            #pragma unroll
            for (int m = 0; m < 16; ++m) d = fmaf(xr[m], llc[j][m], d);
            em[j] = d - ls[j];
            vm = fmaxf(vm, em[j]);
        }
        vm = waveMax64(vm);
        if (lane == 0) red[wv] = vm;
        __syncthreads();
        float Dem = fmaxf(fmaxf(red[0], red[1]), fmaxf(red[2], red[3]));
        uint4 w;
        w.x = pkbf(__expf(em[0]-Dem), __expf(em[1]-Dem));
        w.y = pkbf(__expf(em[2]-Dem), __expf(em[3]-Dem));
        w.z = pkbf(__expf(em[4]-Dem), __expf(em[5]-Dem));
        w.w = pkbf(__expf(em[6]-Dem), __expf(em[7]-Dem));
        *(uint4*)(P + (size_t)t * SD + tid * 8) = w;
        if (tid == 0) sumD += (double)Dem;
        __syncthreads();
    }
    if (tid == 0) atomicAdd(SumAux, (float)sumD);
}

// ---- K3: sequential recurrence, 512 threads / 8 waves ----
// Per step: S1 (1 MFMA, contract p1) -> B1 -> S23 (4 chained MFMAs, contract
// (p2,p3)=128 with A2(x)A3 constants, fp32 accum) + pointwise -> B2.
// alpha stored transposed: albf[c = p2*8+p3][k = p1], 1-bit kblock swizzle.
// C1 stored [d1][c], 4-bit 8-short-block swizzle phys = block ^ d1.
__global__ __launch_bounds__(512, 2)
void fhmm_forward_kernel(const ushort* __restrict__ P,
                         const float* __restrict__ SumAux,
                         const float* __restrict__ logA1,
                         const float* __restrict__ logA2,
                         const float* __restrict__ logA3,
                         const float* __restrict__ logpi1,
                         const float* __restrict__ logpi2,
                         const float* __restrict__ logpi3,
                         float* __restrict__ out)
{
    __shared__ __align__(16) short albf[128 * 16];
    __shared__ __align__(16) short c1b[16 * 128];
    __shared__ __align__(16) short zbuf[8];
    __shared__ float wmA[8];
    __shared__ float sD[1];
    __shared__ float sred[8];

    const int tid  = threadIdx.x;
    const int lane = tid & 63;
    const int wv   = tid >> 6;
    const int q    = lane >> 4;
    const int ml   = lane & 15;

    if (tid < 8) zbuf[tid] = 0;

    // S1 constants: B[k=p1][n=d1'] = A1[d1'=ml][p1=8q+j] (k>=16 zero)
    short8 bA1;
    #pragma unroll
    for (int j = 0; j < 8; ++j) {
        int k = 8 * q + j;
        bA1[j] = (k < 16) ? f2bfs(__expf(logA1[ml * 16 + k])) : (short)0;
    }

    // S23 constants, 4 K-chunks: global k' = 32*jc + 8q + i -> p2 = 4*jc+q, p3 = i
    // n = ml -> d2' = 2wv + (ml>>3), d3' = ml&7; val = exp(logA2 + logA3)
    const int d2p = 2 * wv + (ml >> 3);
    const int d3p = ml & 7;
    short8 bK[4];
    #pragma unroll
    for (int jc = 0; jc < 4; ++jc)
        #pragma unroll
        for (int i = 0; i < 8; ++i)
            bK[jc][i] = f2bfs(__expf(logA2[d2p * 16 + 4 * jc + q] + logA3[d3p * 8 + i]));

    // S1 A-frag: row c = 16wv+ml, kblock q (q<2 real), phys = q ^ ((ml>>3)&1)
    const short* pS1 = (q < 2)
        ? &albf[(16 * wv + ml) * 16 + ((q ^ ((ml >> 3) & 1)) << 3)] : zbuf;
    // S1 D write: C1 row = ml (=d1'), c-block = 2wv + (q>>1), phys = block ^ ml
    short* wS1 = &c1b[ml * 128 + ((((2 * wv + (q >> 1)) ^ ml) & 15) << 3) + 4 * (q & 1)];
    // S23 A-frags: row = ml (=d1), chunk jc: block = 4*jc+q, phys = block ^ ml
    const short* pS23[4];
    #pragma unroll
    for (int jc = 0; jc < 4; ++jc)
        pS23[jc] = &c1b[ml * 128 + ((((4 * jc + q) ^ ml) & 15) << 3)];
    // S23 D write: albf row cc = 16wv+ml, d1-blocks 4q..4q+3:
    // kblock = q>>1, phys = (q>>1) ^ ((cc>>3)&1), offset 4*(q&1)
    const int cc = 16 * wv + ml;
    short* wO = &albf[cc * 16 + (((q >> 1) ^ ((cc >> 3) & 1)) << 3) + 4 * (q & 1)];

    __syncthreads();   // zbuf ready

    // ---- t = 0: alpha0 = P0 * pi ----
    double OFF = 0.0;
    float nu0, nu1, nu2, nu3;
    {
        uintx2 p0 = *(const uintx2*)(P + (size_t)tid * 4);
        float lp23 = logpi2[d2p] + logpi3[d3p];
        nu0 = bfl(p0.x) * __expf(logpi1[4 * q + 0] + lp23);
        nu1 = bfh(p0.x) * __expf(logpi1[4 * q + 1] + lp23);
        nu2 = bfl(p0.y) * __expf(logpi1[4 * q + 2] + lp23);
        nu3 = bfh(p0.y) * __expf(logpi1[4 * q + 3] + lp23);
        ((uintx2*)wO)[0] = (uintx2){pkbf(nu0, nu1), pkbf(nu2, nu3)};
        float wa = waveMax64(fmaxf(fmaxf(nu0, nu1), fmaxf(nu2, nu3)));
        if (lane == 0) wmA[wv] = wa;
        __syncthreads();
    }

    uintx2 Pc = *(const uintx2*)(P + (size_t)2048 + tid * 4);

    // ---- sequential recurrence: 2 barriers/step ----
    for (int t = 1; t < TMAX; ++t) {
        int tn = (t + 1 < TMAX) ? t + 1 : t;
        uintx2 Pn = *(const uintx2*)(P + (size_t)tn * 2048 + tid * 4);

        // wave 0: combine prev alpha maxes -> publish inv scale, accumulate OFF
        if (wv == 0) {
            float mp = waveMax64(wmA[lane & 7]);
            if (lane == 0) {
                float mg = fmaxf(mp, 1e-30f);
                sD[0] = __builtin_amdgcn_rcpf(mg);
                OFF += (double)__logf(mg);
            }
        }

        // Stage 1: C1[d1'][c] = sum_p1 A1[d1',p1] * alpha[p1][c]
        {
            short8 af = *(const short8*)pS1;
            floatx4 acc = {0.f, 0.f, 0.f, 0.f};
            acc = __builtin_amdgcn_mfma_f32_16x16x32_bf16(af, bA1, acc, 0, 0, 0);
            ((uintx2*)wS1)[0] = (uintx2){pkbf(acc[0], acc[1]), pkbf(acc[2], acc[3])};
        }
        __syncthreads();   // B1: C1 + sD ready

        // Stage 2+3 fused: alpha'[d1][ (d2',d3') ] = sum_c C1[d1][c] * (A2 x A3)[c][n]
        {
            floatx4 acc = {0.f, 0.f, 0.f, 0.f};
            acc = __builtin_amdgcn_mfma_f32_16x16x32_bf16(*(const short8*)pS23[0], bK[0], acc, 0, 0, 0);
            acc = __builtin_amdgcn_mfma_f32_16x16x32_bf16(*(const short8*)pS23[1], bK[1], acc, 0, 0, 0);
            acc = __builtin_amdgcn_mfma_f32_16x16x32_bf16(*(const short8*)pS23[2], bK[2], acc, 0, 0, 0);
            acc = __builtin_amdgcn_mfma_f32_16x16x32_bf16(*(const short8*)pS23[3], bK[3], acc, 0, 0, 0);
            float inv = sD[0];
            nu0 = bfl(Pc.x) * acc[0] * inv;
            nu1 = bfh(Pc.x) * acc[1] * inv;
            nu2 = bfl(Pc.y) * acc[2] * inv;
            nu3 = bfh(Pc.y) * acc[3] * inv;
            ((uintx2*)wO)[0] = (uintx2){pkbf(nu0, nu1), pkbf(nu2, nu3)};
            float wa = waveMax64(fmaxf(fmaxf(nu0, nu1), fmaxf(nu2, nu3)));
            if (lane == 0) wmA[wv] = wa;
        }
        Pc = Pn;
        __syncthreads();   // B2: alpha + wmA ready
    }

    // ---- final: logp = OFF + log(sum alpha) + (SumDem - Sumlgamma) ----
    {
        float su = waveSumF(nu0 + nu1 + nu2 + nu3);
        if (lane == 0) sred[wv] = su;
        __syncthreads();
        if (tid == 0) {
            float tot = 0.f;
            #pragma unroll
            for (int i = 0; i < 8; ++i) tot += sred[i];
            out[0] = (float)(OFF + (double)__logf(tot) + (double)SumAux[0]);
        }
    }
}

extern "C" void kernel_launch(void* const* d_in, const int* in_sizes, int n_in,
                              void* d_out, int out_size, void* d_ws, size_t ws_size,
                              hipStream_t stream) {
    const int*   x      = (const int*)  d_in[0];
    const float* lam1   = (const float*)d_in[1];
    const float* lam2   = (const float*)d_in[2];
    const float* lam3   = (const float*)d_in[3];
    const float* logA1  = (const float*)d_in[4];
    const float* logA2  = (const float*)d_in[5];
    const float* logA3  = (const float*)d_in[6];
    const float* logpi1 = (const float*)d_in[7];
    const float* logpi2 = (const float*)d_in[8];
    const float* logpi3 = (const float*)d_in[9];
    float* out = (float*)d_out;

    // ws: [SumAux (256B)] [xf: 1MB] [P_perm: TMAX*2048*2B = 64MB]
    float*  SumAux = (float*)d_ws;
    float*  xf     = (float*)((char*)d_ws + 256);
    ushort* P      = (ushort*)((char*)d_ws + 256 + (size_t)TMAX * MDIM * 4);

    hipMemsetAsync(SumAux, 0, sizeof(float), stream);
    xf_kernel  <<<dim3(256), dim3(256), 0, stream>>>(x, xf);
    lgam_kernel<<<dim3(256), dim3(256), 0, stream>>>(x, SumAux);
    emP_kernel <<<dim3(TMAX / 64), dim3(256), 0, stream>>>(xf, lam1, lam2, lam3, P, SumAux);
    fhmm_forward_kernel<<<dim3(1), dim3(512), 0, stream>>>(
        P, SumAux, logA1, logA2, logA3, logpi1, logpi2, logpi3, out);
}